// Round 7
// baseline (151.498 us; speedup 1.0000x reference)
//
#include <hip/hip_runtime.h>
#include <hip/hip_bf16.h>
#include <stdint.h>

// Problem constants
#define TOKS   262144      // B*S = 32*8192
#define NGRP   16384       // B*G = 32*512
#define EMB    1024
#define HD     64

using bf16x8 = __attribute__((ext_vector_type(8))) short;   // 8 bf16 (4 VGPRs) MFMA operand
using f32x4  = __attribute__((ext_vector_type(4))) float;   // MFMA accumulator

__device__ __forceinline__ unsigned pack2(float a, float b) {
    union { __hip_bfloat162 h; unsigned u; } cvt;
    cvt.h = __float22bfloat162_rn(make_float2(a, b));   // RNE pk-convert
    return cvt.u;
}
__device__ __forceinline__ bf16x8 cvt8(float4 v0, float4 v1) {
    uint4 u;
    u.x = pack2(v0.x, v0.y);
    u.y = pack2(v0.z, v0.w);
    u.z = pack2(v1.x, v1.y);
    u.w = pack2(v1.z, v1.w);
    return __builtin_bit_cast(bf16x8, u);
}
// 3-term row swizzle: 16B-chunk XOR mask within each 128B (64-el) stripe.
// Decorrelates ALL access sets of this kernel: writes rows 16q+gbq+4j (4
// distinct masks over q), energy reads rows 4c+gbq (4-way worst), phase-2
// GEMM A-reads rows m*16+c (2-way), K-scratch rows c (2-way).
__device__ __forceinline__ int swz(int r) {
    return ((r ^ (r >> 2) ^ (r >> 4)) & 7) << 3;
}

// ---------------------------------------------------------------------------
// K0: pack Wo (fp32 [1024][1024]) into MFMA-fragment-linear bf16 (blocks 0..511):
//       packed[((kc*64 + nb)*64 + l)*8 + e] = bf16(Wo[nb*16 + (l&15)][kc*32 + (l>>4)*8 + e])
//     Wq|Wk|Wv (fp32 [64][64]) -> bf16 packed [3][4096] (blocks 512..523).
// ---------------------------------------------------------------------------
__global__ __launch_bounds__(256) void k_cvt(const float* __restrict__ wo,
                                             const float* __restrict__ wq,
                                             const float* __restrict__ wk,
                                             const float* __restrict__ wv,
                                             unsigned short* __restrict__ wob,
                                             unsigned short* __restrict__ wqkvb) {
    int bid = blockIdx.x;
    if (bid < 512) {
        int tid = bid * 256 + threadIdx.x;   // 0..131071, 8 elems each
        int kc  = tid >> 12;                 // k-chunk of 32, 0..31
        int nb  = (tid >> 6) & 63;           // n-block of 16
        int l   = tid & 63;                  // lane within fragment
        int n   = nb * 16 + (l & 15);
        int k   = kc * 32 + (l >> 4) * 8;
        const float* src = wo + (size_t)n * 1024 + k;
        float4 v0 = *(const float4*)(src);
        float4 v1 = *(const float4*)(src + 4);
        *(bf16x8*)(wob + (size_t)tid * 8) = cvt8(v0, v1);
    } else {
        int b = bid - 512;                  // 0..11
        int m = b >> 2;
        const float* src = (m == 0) ? wq : ((m == 1) ? wk : wv);
        int idx = ((b & 3) * 256 + threadIdx.x) * 4;
        float4 v = *(const float4*)(src + idx);
        uint2 p;
        p.x = pack2(v.x, v.y);
        p.y = pack2(v.z, v.w);
        *(uint2*)(wqkvb + m * 4096 + idx) = p;
    }
}

// ---------------------------------------------------------------------------
// K1 (MEGA): fully fused attention + output GEMM. Grid 256 blocks x 512 thr.
// Round-7 changes vs round 6 (k_mega 61us: phase1 ~44us latency-bound serial
// chain, phase2 ~17us near its MFMA+L2 floor; bank conflicts 3.1M):
//  1. Phase 1 processes groups in INTERLEAVED PAIRS (4 iterations of 2
//     independent chains — round-0-proven ILP structure) with explicit
//     x-prefetch of the next pair issued right after the current pair's
//     cvt, hiding the ~300-900cy load latency under proj/energy/PV.
//     Q/V weight frags loaded once per pair (shared by both groups).
//     K-scratch (2KB/wave) time-shared: K(g0)->energy(g0)->K(g1)->energy(g1)
//     — same-wave DS ordering makes the overwrite safe.
//  2. swz() 3-term swizzle everywhere (see above) — fixes the 8-way energy
//     read and the 2-mask store degeneracy of the old (row&7)<<3.
// Arithmetic order is bit-identical to rounds 2-6 (same absmax).
// ---------------------------------------------------------------------------
#define SCL 0.0450842200278f   /* log2(e)/32 */

#define MFMA_B16(A, B, Cc) __builtin_amdgcn_mfma_f32_16x16x32_bf16(A, B, Cc, 0, 0, 0)

__global__ __launch_bounds__(512, 2) void k_mega(const float* __restrict__ x,
                                                 const unsigned short* __restrict__ wqkv,
                                                 const unsigned short* __restrict__ wob,
                                                 const float* __restrict__ bias,
                                                 float* __restrict__ C) {
    extern __shared__ __align__(16) unsigned short lds[];
    unsigned short* out2s = lds;               // [64][1024] bf16 A-tile (128 KB)
    unsigned short* kscr  = lds + 65536;       // [8 waves][16][64] K-scratch (16 KB)

    const int t = threadIdx.x;
    const int w = t >> 6, l = t & 63;
    const int c = l & 15, q = l >> 4;
    const int bid   = blockIdx.x;
    const int batch = bid >> 3, q8 = bid & 3 + 0, q8r = bid & 7;
    unsigned short* kw = kscr + w * 1024;

    const int gbq = w >> 1;                    // wave-constant local group-block
    const int gc0 = (w & 1) * 8;               // wave's first column stripe

    // store masks for the 4 token-rows of a q-quadrant: rows 16q+gbq+4j
    const int mS0 = swz(16 * q + gbq);
    const int mS1 = swz(16 * q + gbq + 4);
    const int mS2 = swz(16 * q + gbq + 8);
    const int mS3 = swz(16 * q + gbq + 12);
    const int mkw = swz(c);                    // K-scratch read mask (row c)
    const int mqe = swz(c * 4 + gbq);          // energy Q-read mask (row 4c+gbq)
    const int mk0 = swz(4 * q);                // K-scratch write masks (rows 4q+j)
    const int mk1 = swz(4 * q + 1);
    const int mk2 = swz(4 * q + 2);
    const int mk3 = swz(4 * q + 3);

    // ================= phase 1: attention, 4 interleaved pairs ============
    const float* xb = x + ((size_t)bid * 1024 + c) * 64 + q * 8;

    float4 xr[2][4];
    #pragma unroll
    for (int g = 0; g < 2; ++g) {
        const float* xp = xb + (size_t)(w * 8 + g) * 1024;
        xr[g][0] = *(const float4*)(xp);
        xr[g][1] = *(const float4*)(xp + 4);
        xr[g][2] = *(const float4*)(xp + 32);
        xr[g][3] = *(const float4*)(xp + 36);
    }

    #pragma unroll 1
    for (int p = 0; p < 4; ++p) {
        // ---- convert current pair, then immediately issue next pair's loads
        bf16x8 xa[2][2];
        #pragma unroll
        for (int g = 0; g < 2; ++g) {
            xa[g][0] = cvt8(xr[g][0], xr[g][1]);
            xa[g][1] = cvt8(xr[g][2], xr[g][3]);
        }
        if (p < 3) {
            #pragma unroll
            for (int g = 0; g < 2; ++g) {
                const float* xp = xb + (size_t)(w * 8 + 2 * (p + 1) + g) * 1024;
                xr[g][0] = *(const float4*)(xp);
                xr[g][1] = *(const float4*)(xp + 4);
                xr[g][2] = *(const float4*)(xp + 32);
                xr[g][3] = *(const float4*)(xp + 36);
            }
        }

        unsigned short* qs[2];
        qs[0] = out2s + (size_t)(16 * q + gbq) * 1024 + (gc0 + 2 * p) * 64;
        qs[1] = qs[0] + 64;

        // ---- Q projection (both groups; W-frags shared) ----
        #pragma unroll
        for (int nb = 0; nb < 4; ++nb) {
            const unsigned short* wp = wqkv + (nb * 16 + c) * 64 + q * 8;
            bf16x8 w0 = *(const bf16x8*)(wp);
            bf16x8 w1 = *(const bf16x8*)(wp + 32);
            #pragma unroll
            for (int g = 0; g < 2; ++g) {
                f32x4 acc = (f32x4){0.f, 0.f, 0.f, 0.f};
                acc = MFMA_B16(xa[g][0], w0, acc);
                acc = MFMA_B16(xa[g][1], w1, acc);
                unsigned u01 = pack2(acc[0], acc[1]);
                unsigned u23 = pack2(acc[2], acc[3]);
                const int d = nb * 16 + c;
                qs[g][(d ^ mS0)]             = (unsigned short)u01;
                qs[g][4 * 1024 + (d ^ mS1)]  = (unsigned short)(u01 >> 16);
                qs[g][8 * 1024 + (d ^ mS2)]  = (unsigned short)u23;
                qs[g][12 * 1024 + (d ^ mS3)] = (unsigned short)(u23 >> 16);
            }
        }

        // ---- V projection (both groups) -> regs ----
        uint2 pkV[2][4];
        #pragma unroll
        for (int nb = 0; nb < 4; ++nb) {
            const unsigned short* wp = wqkv + 2 * 4096 + (nb * 16 + c) * 64 + q * 8;
            bf16x8 w0 = *(const bf16x8*)(wp);
            bf16x8 w1 = *(const bf16x8*)(wp + 32);
            #pragma unroll
            for (int g = 0; g < 2; ++g) {
                f32x4 acc = (f32x4){0.f, 0.f, 0.f, 0.f};
                acc = MFMA_B16(xa[g][0], w0, acc);
                acc = MFMA_B16(xa[g][1], w1, acc);
                pkV[g][nb].x = pack2(acc[0], acc[1]);
                pkV[g][nb].y = pack2(acc[2], acc[3]);
            }
        }

        // ---- K projection + energy, per group (shared kw scratch) ----
        f32x4 e[2];
        #pragma unroll
        for (int g = 0; g < 2; ++g) {
            #pragma unroll
            for (int nb = 0; nb < 4; ++nb) {
                const unsigned short* wp = wqkv + 4096 + (nb * 16 + c) * 64 + q * 8;
                bf16x8 w0 = *(const bf16x8*)(wp);
                bf16x8 w1 = *(const bf16x8*)(wp + 32);
                f32x4 acc = (f32x4){0.f, 0.f, 0.f, 0.f};
                acc = MFMA_B16(xa[g][0], w0, acc);
                acc = MFMA_B16(xa[g][1], w1, acc);
                unsigned u01 = pack2(acc[0], acc[1]);
                unsigned u23 = pack2(acc[2], acc[3]);
                const int d = nb * 16 + c;
                const int kr = 4 * q;
                kw[(kr + 0) * 64 + (d ^ mk0)] = (unsigned short)u01;
                kw[(kr + 1) * 64 + (d ^ mk1)] = (unsigned short)(u01 >> 16);
                kw[(kr + 2) * 64 + (d ^ mk2)] = (unsigned short)u23;
                kw[(kr + 3) * 64 + (d ^ mk3)] = (unsigned short)(u23 >> 16);
            }
            e[g] = (f32x4){0.f, 0.f, 0.f, 0.f};
            const unsigned short* qrow = out2s + (size_t)(c * 4 + gbq) * 1024
                                               + (gc0 + 2 * p + g) * 64;
            #pragma unroll
            for (int kc2 = 0; kc2 < 2; ++kc2) {
                const int L = kc2 * 32 + q * 8;
                bf16x8 ka = *(const bf16x8*)(kw + c * 64 + (L ^ mkw));
                bf16x8 qb = *(const bf16x8*)(qrow + (L ^ mqe));
                e[g] = MFMA_B16(ka, qb, e[g]);
            }
        }
        // lane(q,c): e[g][r] = energy[i=c][j=4q+r]

        // ---- softmax (both groups) ----
        unsigned pa0[2], pa1[2];
        #pragma unroll
        for (int g = 0; g < 2; ++g) {
            float mx = fmaxf(fmaxf(e[g][0], e[g][1]), fmaxf(e[g][2], e[g][3]));
            mx = fmaxf(mx, __shfl_xor(mx, 16));
            mx = fmaxf(mx, __shfl_xor(mx, 32));
            float p0 = exp2f((e[g][0] - mx) * SCL);
            float p1 = exp2f((e[g][1] - mx) * SCL);
            float p2 = exp2f((e[g][2] - mx) * SCL);
            float p3 = exp2f((e[g][3] - mx) * SCL);
            float s = p0 + p1 + p2 + p3;
            s += __shfl_xor(s, 16);
            s += __shfl_xor(s, 32);
            float rinv = 1.0f / s;
            pa0[g] = pack2(p0 * rinv, p1 * rinv);   // j = 4q+0,1
            pa1[g] = pack2(p2 * rinv, p3 * rinv);   // j = 4q+2,3
        }

        // ---- PV (both groups); output overwrites the Q stripe ----
        const int sh0 = (32 * q + c) & 63;
        const int sh1 = (32 * q + 16 + c) & 63;
        const int sv0 = 32 * (q & 1) + c;
        const int sv1 = sv0 + 16;
        const bool hi = (q >= 2);                   // k >= 16 -> zero pad
        #pragma unroll
        for (int g = 0; g < 2; ++g) {
            int a0 = __shfl((int)pa0[g], sh0);
            int a1 = __shfl((int)pa1[g], sh0);
            int a2 = __shfl((int)pa0[g], sh1);
            int a3 = __shfl((int)pa1[g], sh1);
            uint4 A2u;
            A2u.x = hi ? 0u : (unsigned)a0;
            A2u.y = hi ? 0u : (unsigned)a1;
            A2u.z = hi ? 0u : (unsigned)a2;
            A2u.w = hi ? 0u : (unsigned)a3;
            bf16x8 A2 = __builtin_bit_cast(bf16x8, A2u);

            #pragma unroll
            for (int nb = 0; nb < 4; ++nb) {
                uint4 B2u;
                B2u.x = (unsigned)__shfl((int)pkV[g][nb].x, sv0);
                B2u.y = (unsigned)__shfl((int)pkV[g][nb].y, sv0);
                B2u.z = (unsigned)__shfl((int)pkV[g][nb].x, sv1);
                B2u.w = (unsigned)__shfl((int)pkV[g][nb].y, sv1);
                bf16x8 B2 = __builtin_bit_cast(bf16x8, B2u);
                f32x4 o = (f32x4){0.f, 0.f, 0.f, 0.f};
                o = MFMA_B16(A2, B2, o);
                unsigned u01 = pack2(o[0], o[1]);
                unsigned u23 = pack2(o[2], o[3]);
                const int d = nb * 16 + c;
                qs[g][(d ^ mS0)]             = (unsigned short)u01;
                qs[g][4 * 1024 + (d ^ mS1)]  = (unsigned short)(u01 >> 16);
                qs[g][8 * 1024 + (d ^ mS2)]  = (unsigned short)u23;
                qs[g][12 * 1024 + (d ^ mS3)] = (unsigned short)(u23 >> 16);
            }
        }
    }

    __syncthreads();   // A-tile complete

    // ================= phase 2: GEMM  C[64][1024] = A @ Wo^T + bias =======
    // wave w: all 64 rows x cols [w*128, w*128+128). No barriers, no staging.
    const unsigned short* gBw = wob + (size_t)(w * 8) * 512 + (size_t)l * 8;
    float bc[8];
    #pragma unroll
    for (int nb = 0; nb < 8; ++nb) bc[nb] = bias[w * 128 + nb * 16 + c];

    f32x4 acc[4][8];
    #pragma unroll
    for (int m = 0; m < 4; ++m)
        #pragma unroll
        for (int nb = 0; nb < 8; ++nb)
            acc[m][nb] = (f32x4){0.f, 0.f, 0.f, 0.f};

    bf16x8 bE[8], bO[8], a[4];

    #pragma unroll
    for (int nb = 0; nb < 8; ++nb) bE[nb] = *(const bf16x8*)(gBw + nb * 512);   // kc=0

    #pragma unroll 1
    for (int tt = 0; tt < 16; ++tt) {
        const size_t kb = (size_t)tt * 65536;
        #pragma unroll
        for (int nb = 0; nb < 8; ++nb)          // prefetch odd kc = 2tt+1
            bO[nb] = *(const bf16x8*)(gBw + kb + 32768 + nb * 512);
        {
            const int L = (2 * tt) * 32 + q * 8;
            #pragma unroll
            for (int m = 0; m < 4; ++m)
                a[m] = *(const bf16x8*)(out2s + (size_t)(m * 16 + c) * 1024
                                              + (L ^ swz(m * 16 + c)));
            #pragma unroll
            for (int m = 0; m < 4; ++m)
                #pragma unroll
                for (int nb = 0; nb < 8; ++nb)
                    acc[m][nb] = MFMA_B16(a[m], bE[nb], acc[m][nb]);
        }
        if (tt < 15) {
            #pragma unroll
            for (int nb = 0; nb < 8; ++nb)      // prefetch even kc = 2tt+2
                bE[nb] = *(const bf16x8*)(gBw + kb + 65536 + nb * 512);
        }
        {
            const int L = (2 * tt + 1) * 32 + q * 8;
            #pragma unroll
            for (int m = 0; m < 4; ++m)
                a[m] = *(const bf16x8*)(out2s + (size_t)(m * 16 + c) * 1024
                                              + (L ^ swz(m * 16 + c)));
            #pragma unroll
            for (int m = 0; m < 4; ++m)
                #pragma unroll
                for (int nb = 0; nb < 8; ++nb)
                    acc[m][nb] = MFMA_B16(a[m], bO[nb], acc[m][nb]);
        }
    }

    // ---- epilogue: bias + fp32 store. Local row lr = m*16 + q*4 + r:
    //      rg = batch*512 + (4m+q)*32 + (bid&7)*4 + r.
    #pragma unroll
    for (int m = 0; m < 4; ++m) {
        #pragma unroll
        for (int r = 0; r < 4; ++r) {
            const int rg = batch * 512 + (m * 4 + q) * 32 + q8r * 4 + r;
            float* cp = C + (size_t)rg * 1024 + w * 128 + c;
            #pragma unroll
            for (int nb = 0; nb < 8; ++nb)
                cp[nb * 16] = acc[m][nb][r] + bc[nb];
        }
    }
}

// ---------------------------------------------------------------------------
extern "C" void kernel_launch(void* const* d_in, const int* in_sizes, int n_in,
                              void* d_out, int out_size, void* d_ws, size_t ws_size,
                              hipStream_t stream) {
    const float* x  = (const float*)d_in[0];
    const float* wq = (const float*)d_in[1];
    const float* wk = (const float*)d_in[2];
    const float* wv = (const float*)d_in[3];
    const float* wo = (const float*)d_in[4];
    const float* bo = (const float*)d_in[5];
    float* out = (float*)d_out;

    unsigned short* wob   = (unsigned short*)d_ws;           // 1024*1024 bf16 packed (2 MB)
    unsigned short* wqkvb = wob + (size_t)EMB * EMB;         // 3*4096 bf16 (24 KB)

    static int s_once = []() {
        hipFuncSetAttribute((const void*)k_mega,
                            hipFuncAttributeMaxDynamicSharedMemorySize, 147456);
        return 0;
    }();
    (void)s_once;

    k_cvt <<<524, 256, 0, stream>>>(wo, wq, wk, wv, wob, wqkvb);
    k_mega<<<256, 512, 147456, stream>>>(x, wqkvb, wob, bo, out);
}